// Round 1
// baseline (289.334 us; speedup 1.0000x reference)
//
#include <hip/hip_runtime.h>
#include <stdint.h>

#define D_MODEL 1024
#define SEQ 2048
#define HALF 1024
#define NSEQ 8      // BATCH*2 half-sequences
#define K_EIG 24

typedef __attribute__((ext_vector_type(8))) short bf16x8;
typedef __attribute__((ext_vector_type(4))) float f32x4;

#define GAS __attribute__((address_space(1)))
#define LAS __attribute__((address_space(3)))

static __device__ __forceinline__ unsigned short f2bf(float f) {
  union { float f; uint32_t u; } v; v.f = f;
  uint32_t u = v.u;
  u += 0x7FFFu + ((u >> 16) & 1u);   // round-to-nearest-even
  return (unsigned short)(u >> 16);
}

// ---------------- x (fp32) -> bf16 ----------------
__global__ void k_convert_x(const float* __restrict__ x, unsigned short* __restrict__ xb, int n4) {
  int idx = blockIdx.x * blockDim.x + threadIdx.x;
  if (idx < n4) {
    float4 v = ((const float4*)x)[idx];
    ushort4 o;
    o.x = f2bf(v.x); o.y = f2bf(v.y); o.z = f2bf(v.z); o.w = f2bf(v.w);
    ((ushort4*)xb)[idx] = o;
  }
}

// ------------- M_inputs [K][N] fp32 -> Mt [N][K] bf16 -------------
__global__ void k_transpose_M(const float* __restrict__ M, unsigned short* __restrict__ Mt) {
  __shared__ float tile[32][33];
  int k0 = blockIdx.y * 32, n0 = blockIdx.x * 32;
  int tx = threadIdx.x & 31, ty = threadIdx.x >> 5;   // 32 x 8
  #pragma unroll
  for (int r = 0; r < 32; r += 8)
    tile[ty + r][tx] = M[(size_t)(k0 + ty + r) * D_MODEL + n0 + tx];
  __syncthreads();
  #pragma unroll
  for (int r = 0; r < 32; r += 8)
    Mt[(size_t)(n0 + ty + r) * D_MODEL + k0 + tx] = f2bf(tile[tx][ty + r]);
}

// ------------- w_e[j][d] = 2 * sum_k phi[2j][k] * Mf[k][d] -------------
__global__ void k_we(const float* __restrict__ phi, const float* __restrict__ Mf,
                     float* __restrict__ we) {
  int j = blockIdx.x;                  // 0..1023
  __shared__ float ph[K_EIG];
  if (threadIdx.x < K_EIG) ph[threadIdx.x] = phi[(size_t)(2 * j) * K_EIG + threadIdx.x];
  __syncthreads();
  for (int d = threadIdx.x; d < D_MODEL; d += blockDim.x) {
    float s = 0.f;
    #pragma unroll
    for (int k = 0; k < K_EIG; ++k) s = fmaf(ph[k], Mf[(size_t)k * D_MODEL + d], s);
    we[(size_t)j * D_MODEL + d] = 2.0f * s;
  }
}

// ------------- u = x @ M  (bf16 MFMA, B^T input), epilogue remaps to u_h[r][i][d] -------------
// C[m][n] = sum_k A[m][k] * Bt[n][k];  M=8192, N=1024, K=1024. 128x128 tile, BK=32.
__global__ __launch_bounds__(256) void k_gemm(const unsigned short* __restrict__ A,
                                              const unsigned short* __restrict__ Bt,
                                              float* __restrict__ U) {
  __shared__ unsigned short As[128 * 32];
  __shared__ unsigned short Bs[128 * 32];
  const int m0 = (int)blockIdx.x * 128;
  const int n0 = (int)blockIdx.y * 128;
  const int tid = threadIdx.x;
  const int lane = tid & 63;
  const int wave = tid >> 6;                 // 0..3
  const int wm = wave >> 1, wn = wave & 1;   // 2x2 wave grid, 64x64 each
  const int srow = lane >> 2;                // staging: 4 lanes per 64B row
  const int skoff = (lane & 3) * 8;

  f32x4 acc[4][4] = {};

  for (int k0 = 0; k0 < 1024; k0 += 32) {
    __syncthreads();
    #pragma unroll
    for (int c = 0; c < 2; ++c) {
      int rbase = wave * 32 + c * 16;
      const unsigned short* src = A + (size_t)(m0 + rbase + srow) * 1024 + k0 + skoff;
      __builtin_amdgcn_global_load_lds((const GAS void*)src, (LAS void*)(As + rbase * 32), 16, 0, 0);
    }
    #pragma unroll
    for (int c = 0; c < 2; ++c) {
      int rbase = wave * 32 + c * 16;
      const unsigned short* src = Bt + (size_t)(n0 + rbase + srow) * 1024 + k0 + skoff;
      __builtin_amdgcn_global_load_lds((const GAS void*)src, (LAS void*)(Bs + rbase * 32), 16, 0, 0);
    }
    __syncthreads();

    bf16x8 a[4], b[4];
    #pragma unroll
    for (int mt = 0; mt < 4; ++mt)
      a[mt] = *(const bf16x8*)(As + ((wm * 64 + mt * 16 + (lane & 15)) * 32 + (lane >> 4) * 8));
    #pragma unroll
    for (int nt = 0; nt < 4; ++nt)
      b[nt] = *(const bf16x8*)(Bs + ((wn * 64 + nt * 16 + (lane & 15)) * 32 + (lane >> 4) * 8));
    #pragma unroll
    for (int mt = 0; mt < 4; ++mt)
      #pragma unroll
      for (int nt = 0; nt < 4; ++nt)
        acc[mt][nt] = __builtin_amdgcn_mfma_f32_16x16x32_bf16(a[mt], b[nt], acc[mt][nt], 0, 0, 0);
  }

  // epilogue: C/D layout col = lane&15, row = (lane>>4)*4 + q. Remap m=(b,t) -> (r, i).
  const int crow = (lane >> 4) * 4;
  const int ccol = lane & 15;
  #pragma unroll
  for (int mt = 0; mt < 4; ++mt) {
    #pragma unroll
    for (int q = 0; q < 4; ++q) {
      int m = m0 + wm * 64 + mt * 16 + crow + q;
      int b_ = m >> 11;
      int t = m & 2047;
      int r = (b_ << 1) | (t & 1);
      int i = t >> 1;
      float* dst = U + ((size_t)(r * HALF + i)) * D_MODEL;
      #pragma unroll
      for (int nt = 0; nt < 4; ++nt)
        dst[n0 + wn * 64 + nt * 16 + ccol] = acc[mt][nt][q];
    }
  }
}

// ------------- depthwise causal conv over half-sequences (fp32, sliding window) -------------
// out_h[r][i][d] = sum_{j<=i} we[j][d] * u_h[r][i-j][d]
// block: 256 thr = 64 d-lanes x 4 waves (each wave = 32 consecutive i's). i-tile = 128.
__global__ __launch_bounds__(256) void k_conv(const float* __restrict__ u,
                                              const float* __restrict__ we,
                                              float* __restrict__ out) {
  __shared__ float u_s[192][64];   // phys rows [i0-jc-64, i0-jc+128)
  __shared__ float w_s[64][64];    // taps [jc, jc+64)
  const int r  = blockIdx.z;           // 0..7
  const int d0 = blockIdx.y * 64;      // 16 tiles
  const int i0 = blockIdx.x * 128;     // 8 tiles
  const int tid = threadIdx.x;
  const int dl = tid & 63;
  const int ig = tid >> 6;             // wave id = i-subgroup
  const int ibase = i0 + ig * 32;

  const int pr_ = tid >> 4;            // staging: 16 rows/pass
  const int pc  = (tid & 15) * 4;

  float acc[32];
  #pragma unroll
  for (int o = 0; o < 32; ++o) acc[o] = 0.f;

  // circular window: win[row & 31] = u_h[r][row][d0+dl] for row in [ibase-j, ibase-j+31]
  float win[32];
  #pragma unroll
  for (int o = 0; o < 32; ++o)
    win[o] = u[((size_t)(r * HALF + ibase + o)) * D_MODEL + d0 + dl];  // ibase%32==0 -> slot==o

  for (int jc = 0; jc <= i0 + 127; jc += 64) {
    __syncthreads();
    // stage u: 192 rows, zero-pad phys<0
    #pragma unroll
    for (int pass = 0; pass < 12; ++pass) {
      int rr = pass * 16 + pr_;
      int phys = i0 - jc - 64 + rr;
      float4 v = make_float4(0.f, 0.f, 0.f, 0.f);
      if (phys >= 0)
        v = *(const float4*)&u[((size_t)(r * HALF + phys)) * D_MODEL + d0 + pc];
      *(float4*)&u_s[rr][pc] = v;
    }
    // stage w: 64 taps
    #pragma unroll
    for (int pass = 0; pass < 4; ++pass) {
      int rr = pass * 16 + pr_;
      *(float4*)&w_s[rr][pc] = *(const float4*)&we[(size_t)(jc + rr) * D_MODEL + d0 + pc];
    }
    __syncthreads();

    #pragma unroll
    for (int jj0 = 0; jj0 < 64; jj0 += 32) {
      #pragma unroll
      for (int k = 0; k < 32; ++k) {
        float wv = w_s[jj0 + k][dl];
        #pragma unroll
        for (int o = 0; o < 32; ++o)
          acc[o] = fmaf(wv, win[(o - k) & 31], acc[o]);
        // slide: insert row ibase - j - 1 at slot 31-k (j = jc + jj0 + k)
        win[31 - k] = u_s[ig * 32 + 63 - jj0 - k][dl];
      }
    }
  }

  const int b_ = r >> 1, p = r & 1;
  #pragma unroll
  for (int o = 0; o < 32; ++o) {
    int t = 2 * (ibase + o) + p;
    out[((size_t)b_ * SEQ + t) * D_MODEL + d0 + dl] = acc[o];
  }
}

extern "C" void kernel_launch(void* const* d_in, const int* in_sizes, int n_in,
                              void* d_out, int out_size, void* d_ws, size_t ws_size,
                              hipStream_t stream) {
  const float* x   = (const float*)d_in[0];   // [4][2048][1024]
  const float* Mi  = (const float*)d_in[1];   // [1024][1024]
  const float* Mf  = (const float*)d_in[2];   // [24][1024]
  const float* phi = (const float*)d_in[3];   // [2048][24]
  float* out = (float*)d_out;

  char* ws = (char*)d_ws;
  unsigned short* x_bf = (unsigned short*)(ws);                           // 16 MB
  unsigned short* Mt   = (unsigned short*)(ws + (16u << 20));             // 2 MB
  float* we            = (float*)(ws + (16u << 20) + (2u << 20));         // 4 MB
  float* u             = (float*)(ws + (16u << 20) + (2u << 20) + (4u << 20)); // 32 MB

  hipLaunchKernelGGL(k_convert_x, dim3(8192), dim3(256), 0, stream, x, x_bf, 2097152);
  hipLaunchKernelGGL(k_transpose_M, dim3(32, 32), dim3(256), 0, stream, Mi, Mt);
  hipLaunchKernelGGL(k_we, dim3(1024), dim3(256), 0, stream, phi, Mf, we);
  hipLaunchKernelGGL(k_gemm, dim3(64, 8), dim3(256), 0, stream, x_bf, Mt, u);
  hipLaunchKernelGGL(k_conv, dim3(8, 16, 8), dim3(256), 0, stream, u, we, out);
}

// Round 2
// 283.009 us; speedup vs baseline: 1.0223x; 1.0223x over previous
//
#include <hip/hip_runtime.h>
#include <stdint.h>

#define D_MODEL 1024
#define SEQ 2048
#define HALF 1024
#define K_EIG 24

typedef __attribute__((ext_vector_type(8))) short bf16x8;
typedef __attribute__((ext_vector_type(4))) float f32x4;

#define GAS __attribute__((address_space(1)))
#define LAS __attribute__((address_space(3)))

static __device__ __forceinline__ unsigned short f2bf(float f) {
  union { float f; uint32_t u; } v; v.f = f;
  uint32_t u = v.u;
  u += 0x7FFFu + ((u >> 16) & 1u);   // round-to-nearest-even
  return (unsigned short)(u >> 16);
}

// ---------------- x (fp32) -> bf16 ----------------
__global__ void k_convert_x(const float* __restrict__ x, unsigned short* __restrict__ xb, int n4) {
  int idx = blockIdx.x * blockDim.x + threadIdx.x;
  if (idx < n4) {
    float4 v = ((const float4*)x)[idx];
    ushort4 o;
    o.x = f2bf(v.x); o.y = f2bf(v.y); o.z = f2bf(v.z); o.w = f2bf(v.w);
    ((ushort4*)xb)[idx] = o;
  }
}

// ------------- M_inputs [K][N] fp32 -> Mt [N][K] bf16 -------------
__global__ void k_transpose_M(const float* __restrict__ M, unsigned short* __restrict__ Mt) {
  __shared__ float tile[32][33];
  int k0 = blockIdx.y * 32, n0 = blockIdx.x * 32;
  int tx = threadIdx.x & 31, ty = threadIdx.x >> 5;   // 32 x 8
  #pragma unroll
  for (int r = 0; r < 32; r += 8)
    tile[ty + r][tx] = M[(size_t)(k0 + ty + r) * D_MODEL + n0 + tx];
  __syncthreads();
  #pragma unroll
  for (int r = 0; r < 32; r += 8)
    Mt[(size_t)(n0 + ty + r) * D_MODEL + k0 + tx] = f2bf(tile[tx][ty + r]);
}

// ------------- w_e[j][d] = 2 * sum_k phi[2j][k] * Mf[k][d] -------------
__global__ void k_we(const float* __restrict__ phi, const float* __restrict__ Mf,
                     float* __restrict__ we) {
  int j = blockIdx.x;                  // 0..1023
  __shared__ float ph[K_EIG];
  if (threadIdx.x < K_EIG) ph[threadIdx.x] = phi[(size_t)(2 * j) * K_EIG + threadIdx.x];
  __syncthreads();
  for (int d = threadIdx.x; d < D_MODEL; d += blockDim.x) {
    float s = 0.f;
    #pragma unroll
    for (int k = 0; k < K_EIG; ++k) s = fmaf(ph[k], Mf[(size_t)k * D_MODEL + d], s);
    we[(size_t)j * D_MODEL + d] = 2.0f * s;
  }
}

// ------------- u = x @ M  (bf16 MFMA, B^T input), epilogue remaps to u_h[r][i][d] -------------
__global__ __launch_bounds__(256) void k_gemm(const unsigned short* __restrict__ A,
                                              const unsigned short* __restrict__ Bt,
                                              float* __restrict__ U) {
  __shared__ unsigned short As[128 * 32];
  __shared__ unsigned short Bs[128 * 32];
  const int m0 = (int)blockIdx.x * 128;
  const int n0 = (int)blockIdx.y * 128;
  const int tid = threadIdx.x;
  const int lane = tid & 63;
  const int wave = tid >> 6;                 // 0..3
  const int wm = wave >> 1, wn = wave & 1;   // 2x2 wave grid, 64x64 each
  const int srow = lane >> 2;                // staging: 4 lanes per 64B row
  const int skoff = (lane & 3) * 8;

  f32x4 acc[4][4] = {};

  for (int k0 = 0; k0 < 1024; k0 += 32) {
    __syncthreads();
    #pragma unroll
    for (int c = 0; c < 2; ++c) {
      int rbase = wave * 32 + c * 16;
      const unsigned short* src = A + (size_t)(m0 + rbase + srow) * 1024 + k0 + skoff;
      __builtin_amdgcn_global_load_lds((const GAS void*)src, (LAS void*)(As + rbase * 32), 16, 0, 0);
    }
    #pragma unroll
    for (int c = 0; c < 2; ++c) {
      int rbase = wave * 32 + c * 16;
      const unsigned short* src = Bt + (size_t)(n0 + rbase + srow) * 1024 + k0 + skoff;
      __builtin_amdgcn_global_load_lds((const GAS void*)src, (LAS void*)(Bs + rbase * 32), 16, 0, 0);
    }
    __syncthreads();

    bf16x8 a[4], b[4];
    #pragma unroll
    for (int mt = 0; mt < 4; ++mt)
      a[mt] = *(const bf16x8*)(As + ((wm * 64 + mt * 16 + (lane & 15)) * 32 + (lane >> 4) * 8));
    #pragma unroll
    for (int nt = 0; nt < 4; ++nt)
      b[nt] = *(const bf16x8*)(Bs + ((wn * 64 + nt * 16 + (lane & 15)) * 32 + (lane >> 4) * 8));
    #pragma unroll
    for (int mt = 0; mt < 4; ++mt)
      #pragma unroll
      for (int nt = 0; nt < 4; ++nt)
        acc[mt][nt] = __builtin_amdgcn_mfma_f32_16x16x32_bf16(a[mt], b[nt], acc[mt][nt], 0, 0, 0);
  }

  const int crow = (lane >> 4) * 4;
  const int ccol = lane & 15;
  #pragma unroll
  for (int mt = 0; mt < 4; ++mt) {
    #pragma unroll
    for (int q = 0; q < 4; ++q) {
      int m = m0 + wm * 64 + mt * 16 + crow + q;
      int b_ = m >> 11;
      int t = m & 2047;
      int r = (b_ << 1) | (t & 1);
      int i = t >> 1;
      float* dst = U + ((size_t)(r * HALF + i)) * D_MODEL;
      #pragma unroll
      for (int nt = 0; nt < 4; ++nt)
        dst[n0 + wn * 64 + nt * 16 + ccol] = acc[mt][nt][q];
    }
  }
}

// ------------- depthwise causal conv: register sliding window, no LDS, no barriers -------------
// out_h[r][i][d] = sum_{j<=i} we[j][d] * u_h[r][i-j][d]
// Block: 256 thr = 64 d-lanes x 4 waves (each wave 32 consecutive i's).
// Each block does i-tile pair (a, 7-a): exactly 18 x 64-tap iterations -> perfect balance.
__device__ __forceinline__ void pref_u(const float* __restrict__ ub, int urow, float (&buf)[8]) {
#pragma unroll
  for (int t = 0; t < 8; ++t)
    buf[t] = (urow - t >= 0) ? ub[(size_t)(urow - t) * D_MODEL] : 0.f;
}

__device__ __forceinline__ void pref_w(const float* __restrict__ wb, int wrow, float (&buf)[8]) {
#pragma unroll
  for (int t = 0; t < 8; ++t)
    buf[t] = (wrow + t < HALF) ? wb[(size_t)(wrow + t) * D_MODEL] : 0.f;
}

template <int G8>
__device__ __forceinline__ void tap_group(const float (&cu)[8], const float (&cw)[8],
                                          float (&win)[32], float (&acc)[32]) {
#pragma unroll
  for (int t = 0; t < 8; ++t) {
    const int kf = G8 + t;
    float wv = cw[t];
#pragma unroll
    for (int o = 0; o < 32; ++o)
      acc[o] = fmaf(wv, win[(o - kf) & 31], acc[o]);
    win[(31 - kf) & 31] = cu[t];
  }
}

__global__ __launch_bounds__(256) void k_conv(const float* __restrict__ u,
                                              const float* __restrict__ we,
                                              float* __restrict__ out) {
  const int r  = blockIdx.z;           // 0..7 half-sequences
  const int d0 = blockIdx.y * 64;      // 16 d-tiles
  const int pp = blockIdx.x;           // 0..3 i-tile pairs
  const int tid = threadIdx.x;
  const int dl = tid & 63;
  const int ig = tid >> 6;             // wave id = i-subgroup

  const float* ub = u + (size_t)r * HALF * D_MODEL + d0 + dl;   // +row*D_MODEL
  const float* wb = we + d0 + dl;
  const int b_ = r >> 1, p = r & 1;

#pragma unroll 1
  for (int tt = 0; tt < 2; ++tt) {
    const int a = tt ? pp : (7 - pp);   // heavy tile first, then light: total 18 iters/block
    const int i0 = a * 128;
    const int ibase = i0 + ig * 32;

    float acc[32], win[32];
#pragma unroll
    for (int o = 0; o < 32; ++o) {
      acc[o] = 0.f;
      win[o] = ub[(size_t)(ibase + o) * D_MODEL];
    }

    float bu0[8], bu1[8], bw0[8], bw1[8];
    int urow = ibase - 1, wrow = 0;
    pref_u(ub, urow, bu0); urow -= 8;
    pref_w(wb, wrow, bw0); wrow += 8;

    const int niter = (i0 + 128) >> 6;
#pragma unroll 1
    for (int it = 0; it < niter; ++it) {
      pref_u(ub, urow, bu1); urow -= 8; pref_w(wb, wrow, bw1); wrow += 8;
      tap_group<0>(bu0, bw0, win, acc);
      pref_u(ub, urow, bu0); urow -= 8; pref_w(wb, wrow, bw0); wrow += 8;
      tap_group<8>(bu1, bw1, win, acc);
      pref_u(ub, urow, bu1); urow -= 8; pref_w(wb, wrow, bw1); wrow += 8;
      tap_group<16>(bu0, bw0, win, acc);
      pref_u(ub, urow, bu0); urow -= 8; pref_w(wb, wrow, bw0); wrow += 8;
      tap_group<24>(bu1, bw1, win, acc);
      pref_u(ub, urow, bu1); urow -= 8; pref_w(wb, wrow, bw1); wrow += 8;
      tap_group<32>(bu0, bw0, win, acc);
      pref_u(ub, urow, bu0); urow -= 8; pref_w(wb, wrow, bw0); wrow += 8;
      tap_group<40>(bu1, bw1, win, acc);
      pref_u(ub, urow, bu1); urow -= 8; pref_w(wb, wrow, bw1); wrow += 8;
      tap_group<48>(bu0, bw0, win, acc);
      pref_u(ub, urow, bu0); urow -= 8; pref_w(wb, wrow, bw0); wrow += 8;
      tap_group<56>(bu1, bw1, win, acc);
    }

#pragma unroll
    for (int o = 0; o < 32; ++o)
      out[((size_t)b_ * SEQ + 2 * (ibase + o) + p) * D_MODEL + d0 + dl] = acc[o];
  }
}

extern "C" void kernel_launch(void* const* d_in, const int* in_sizes, int n_in,
                              void* d_out, int out_size, void* d_ws, size_t ws_size,
                              hipStream_t stream) {
  const float* x   = (const float*)d_in[0];   // [4][2048][1024]
  const float* Mi  = (const float*)d_in[1];   // [1024][1024]
  const float* Mf  = (const float*)d_in[2];   // [24][1024]
  const float* phi = (const float*)d_in[3];   // [2048][24]
  float* out = (float*)d_out;

  char* ws = (char*)d_ws;
  unsigned short* x_bf = (unsigned short*)(ws);                           // 16 MB
  unsigned short* Mt   = (unsigned short*)(ws + (16u << 20));             // 2 MB
  float* we            = (float*)(ws + (16u << 20) + (2u << 20));         // 4 MB
  float* u             = (float*)(ws + (16u << 20) + (2u << 20) + (4u << 20)); // 32 MB

  hipLaunchKernelGGL(k_convert_x, dim3(8192), dim3(256), 0, stream, x, x_bf, 2097152);
  hipLaunchKernelGGL(k_transpose_M, dim3(32, 32), dim3(256), 0, stream, Mi, Mt);
  hipLaunchKernelGGL(k_we, dim3(1024), dim3(256), 0, stream, phi, Mf, we);
  hipLaunchKernelGGL(k_gemm, dim3(64, 8), dim3(256), 0, stream, x_bf, Mt, u);
  hipLaunchKernelGGL(k_conv, dim3(4, 16, 8), dim3(256), 0, stream, u, we, out);
}